// Round 10
// baseline (128.486 us; speedup 1.0000x reference)
//
#include <hip/hip_runtime.h>

// Problem shape (fixed by reference): N=64, C=1024, H=W=28 -> HW=784
#define HWD 784
#define Q4  196            // HWD/4 float4 slots per channel row
#define CD  1024
#define ND  64

#define CHPB 32            // channels per pass1 block (4 waves x 8)
#define NCHUNK (CD / CHPB) // 32 partial chunks
#define NBLK (NCHUNK * ND) // 2048 pass1 blocks

typedef float f32x4 __attribute__((ext_vector_type(4)));

__device__ __forceinline__ float4 cam4(float4 v, float wc) {
    float4 r;
    r.x = fmaxf(v.x * wc, 0.f);
    r.y = fmaxf(v.y * wc, 0.f);
    r.z = fmaxf(v.z * wc, 0.f);
    r.w = fmaxf(v.w * wc, 0.f);
    return r;
}
__device__ __forceinline__ float max4(float4 v) {
    return fmaxf(fmaxf(v.x, v.y), fmaxf(v.z, v.w));
}
__device__ __forceinline__ void accdrop(float4& a, float4 c, float thr) {
    a.x += (c.x > thr) ? 0.f : c.x;
    a.y += (c.y > thr) ? 0.f : c.y;
    a.z += (c.z > thr) ? 0.f : c.z;
    a.w += (c.w > thr) ? 0.f : c.w;
}

// ---------------------------------------------------------------------------
// Pass 1: 2048 blocks x 256 threads (4 waves x 8 channels each).
// 1D grid, XCD-chunked swizzle: each XCD streams a contiguous ~25.6MB region.
// Per wave: 8 consecutive channels in 2 phases of 4; 16 float4 loads in
// flight; 4 independent shfl-butterfly max chains; dropped values accumulated
// in registers (position-aligned). LDS combine (non-atomic), coalesced Spart
// store. S-compute rides the mandatory 205MB cold read.
// ---------------------------------------------------------------------------
__global__ void __launch_bounds__(256) pass1_kernel(const float* __restrict__ x,
                                                    const float* __restrict__ w,
                                                    const float* __restrict__ mu_p,
                                                    float* __restrict__ Spart) {
    __shared__ float4 drp[4][197];   // wave stride 197*4 = 788 floats

    const int bid = blockIdx.x;
    const int work = (bid & 7) * (NBLK / 8) + (bid >> 3);   // XCD-contiguous
    const int n = work >> 5;             // sample
    const int chunk = work & 31;         // channel chunk
    const int t = threadIdx.x;
    const int wave = t >> 6;
    const int lane = t & 63;
    const int cbase = chunk * CHPB + wave * 8;
    const float mu = mu_p[0];

    const float4* rows = reinterpret_cast<const float4*>(x + ((size_t)n * CD + cbase) * HWD);

    float4 acc0 = {0.f,0.f,0.f,0.f}, acc1 = {0.f,0.f,0.f,0.f};
    float4 acc2 = {0.f,0.f,0.f,0.f}, acc3 = {0.f,0.f,0.f,0.f};

    #pragma unroll
    for (int ph = 0; ph < 2; ++ph) {
        const float4* r0 = rows + (ph * 4) * Q4;
        const float4* r1 = r0 + Q4;
        const float4* r2 = r1 + Q4;
        const float4* r3 = r2 + Q4;
        float4 a0 = r0[lane], a1 = r0[lane + 64], a2 = r0[lane + 128];
        float4 b0 = r1[lane], b1 = r1[lane + 64], b2 = r1[lane + 128];
        float4 c0 = r2[lane], c1 = r2[lane + 64], c2 = r2[lane + 128];
        float4 d0 = r3[lane], d1 = r3[lane + 64], d2 = r3[lane + 128];
        float4 a3 = {0.f,0.f,0.f,0.f}, b3 = {0.f,0.f,0.f,0.f};
        float4 c3 = {0.f,0.f,0.f,0.f}, d3 = {0.f,0.f,0.f,0.f};
        if (lane < 4) {
            a3 = r0[192 + lane]; b3 = r1[192 + lane];
            c3 = r2[192 + lane]; d3 = r3[192 + lane];
        }

        const float w0 = w[cbase + ph * 4 + 0];
        const float w1 = w[cbase + ph * 4 + 1];
        const float w2 = w[cbase + ph * 4 + 2];
        const float w3 = w[cbase + ph * 4 + 3];

        a0 = cam4(a0, w0); a1 = cam4(a1, w0); a2 = cam4(a2, w0); a3 = cam4(a3, w0);
        b0 = cam4(b0, w1); b1 = cam4(b1, w1); b2 = cam4(b2, w1); b3 = cam4(b3, w1);
        c0 = cam4(c0, w2); c1 = cam4(c1, w2); c2 = cam4(c2, w2); c3 = cam4(c3, w2);
        d0 = cam4(d0, w3); d1 = cam4(d1, w3); d2 = cam4(d2, w3); d3 = cam4(d3, w3);

        float m0 = fmaxf(fmaxf(max4(a0), max4(a1)), fmaxf(max4(a2), max4(a3)));
        float m1 = fmaxf(fmaxf(max4(b0), max4(b1)), fmaxf(max4(b2), max4(b3)));
        float m2 = fmaxf(fmaxf(max4(c0), max4(c1)), fmaxf(max4(c2), max4(c3)));
        float m3 = fmaxf(fmaxf(max4(d0), max4(d1)), fmaxf(max4(d2), max4(d3)));

        #pragma unroll
        for (int off = 32; off > 0; off >>= 1) {
            m0 = fmaxf(m0, __shfl_xor(m0, off, 64));
            m1 = fmaxf(m1, __shfl_xor(m1, off, 64));
            m2 = fmaxf(m2, __shfl_xor(m2, off, 64));
            m3 = fmaxf(m3, __shfl_xor(m3, off, 64));
        }
        const float t0 = m0 * mu, t1 = m1 * mu, t2 = m2 * mu, t3 = m3 * mu;

        accdrop(acc0, a0, t0); accdrop(acc1, a1, t0); accdrop(acc2, a2, t0); accdrop(acc3, a3, t0);
        accdrop(acc0, b0, t1); accdrop(acc1, b1, t1); accdrop(acc2, b2, t1); accdrop(acc3, b3, t1);
        accdrop(acc0, c0, t2); accdrop(acc1, c1, t2); accdrop(acc2, c2, t2); accdrop(acc3, c3, t2);
        accdrop(acc0, d0, t3); accdrop(acc1, d1, t3); accdrop(acc2, d2, t3); accdrop(acc3, d3, t3);
    }

    drp[wave][lane]       = acc0;
    drp[wave][64 + lane]  = acc1;
    drp[wave][128 + lane] = acc2;
    if (lane < 4) drp[wave][192 + lane] = acc3;
    __syncthreads();

    const float* f = reinterpret_cast<const float*>(&drp[0][0]);
    float* sp = Spart + ((size_t)chunk * ND + n) * HWD;
    for (int p = t; p < HWD; p += 256)
        sp[p] = f[p] + f[788 + p] + f[2 * 788 + p] + f[3 * 788 + p];
}

// ---------------------------------------------------------------------------
// Mult (with folded reduce): block = (n, 16-position chunk), 256 threads.
// Prologue: 16 threads sum the 32 Spart partials for this block's positions
// (2KB L2-hot, MLP-32) -> LDS; one barrier. Main: 16 channel-iters of pure
// x-read (L3-hot) + NT out-write: exactly 2 VMEM requests per 16B of output
// (was 3 — per-channel S re-fetch eliminated). 64B-aligned segments.
// ---------------------------------------------------------------------------
__global__ void __launch_bounds__(256) mult_kernel(const float* __restrict__ x,
                                                   const float* __restrict__ Spart,
                                                   float* __restrict__ out) {
    __shared__ float S_lds[16];

    const int t = threadIdx.x;
    const int n = blockIdx.y;
    const int pos0 = blockIdx.x * 16;

    if (t < 16) {
        float s = 0.f;
        #pragma unroll
        for (int ch = 0; ch < NCHUNK; ++ch)
            s += Spart[((size_t)ch * ND + n) * HWD + pos0 + t];
        S_lds[t] = s;
    }
    __syncthreads();

    const int q = t & 3;                 // float4 slot within the 16 positions
    const int g = t >> 2;                // channel offset 0..63
    const float4 sv = *reinterpret_cast<const float4*>(S_lds + q * 4);
    const size_t base = (size_t)n * CD * HWD + pos0 + q * 4;

    #pragma unroll 4
    for (int k = 0; k < 16; ++k) {
        const size_t idx = base + (size_t)(g + (k << 6)) * HWD;
        float4 xv = *reinterpret_cast<const float4*>(x + idx);
        float4 o;
        o.x = xv.x * sv.x;
        o.y = xv.y * sv.y;
        o.z = xv.z * sv.z;
        o.w = xv.w * sv.w;
        __builtin_nontemporal_store(*reinterpret_cast<const f32x4*>(&o),
                                    reinterpret_cast<f32x4*>(out + idx));
    }
}

extern "C" void kernel_launch(void* const* d_in, const int* in_sizes, int n_in,
                              void* d_out, int out_size, void* d_ws, size_t ws_size,
                              hipStream_t stream) {
    const float* x  = (const float*)d_in[0];   // [N, C, H, W] f32
    const float* w  = (const float*)d_in[1];   // [C] f32
    const float* mu = (const float*)d_in[2];   // scalar (1-elem array)
    float* out = (float*)d_out;

    float* Spart = (float*)d_ws;               // 32*64*784*4 = 6.4 MB scratch

    // Pass 1: 2048 blocks (XCD-swizzled), 256 threads
    pass1_kernel<<<NBLK, 256, 0, stream>>>(x, w, mu, Spart);

    // Mult: 49 position-chunks x 64 samples, reduce folded into prologue
    dim3 gm(HWD / 16, ND);
    mult_kernel<<<gm, 256, 0, stream>>>(x, Spart, out);
}

// Round 11
// 99.988 us; speedup vs baseline: 1.2850x; 1.2850x over previous
//
#include <hip/hip_runtime.h>

// Problem shape (fixed by reference): N=64, C=1024, H=W=28 -> HW=784
#define HWD 784
#define Q4  196            // HWD/4 float4 slots per channel row
#define CD  1024
#define ND  64

#define CHPB 32            // channels per pass1 block (4 waves x 8)
#define NCHUNK (CD / CHPB) // 32 partial chunks

typedef float f32x4 __attribute__((ext_vector_type(4)));

__device__ __forceinline__ float4 cam4(float4 v, float wc) {
    float4 r;
    r.x = fmaxf(v.x * wc, 0.f);
    r.y = fmaxf(v.y * wc, 0.f);
    r.z = fmaxf(v.z * wc, 0.f);
    r.w = fmaxf(v.w * wc, 0.f);
    return r;
}
__device__ __forceinline__ float max4(float4 v) {
    return fmaxf(fmaxf(v.x, v.y), fmaxf(v.z, v.w));
}
__device__ __forceinline__ void accdrop(float4& a, float4 c, float thr) {
    a.x += (c.x > thr) ? 0.f : c.x;
    a.y += (c.y > thr) ? 0.f : c.y;
    a.z += (c.z > thr) ? 0.f : c.z;
    a.w += (c.w > thr) ? 0.f : c.w;
}

// ---------------------------------------------------------------------------
// Pass 1 (round-8 known-good): block = (chunk of 32 channels, n), 256 thr.
// Each wave: 8 channels in 2 phases of 4; 16 float4 loads in flight; 4
// independent shfl-butterfly max chains; dropped values accumulated in
// registers. LDS combine, coalesced Spart store. No atomics.
// ---------------------------------------------------------------------------
__global__ void __launch_bounds__(256) pass1_kernel(const float* __restrict__ x,
                                                    const float* __restrict__ w,
                                                    const float* __restrict__ mu_p,
                                                    float* __restrict__ Spart) {
    __shared__ float4 drp[4][197];   // wave stride 197*4 = 788 floats

    const int t = threadIdx.x;
    const int wave = t >> 6;
    const int lane = t & 63;
    const int n = blockIdx.y;
    const int cbase = blockIdx.x * CHPB + wave * 8;
    const float mu = mu_p[0];

    const float4* rows = reinterpret_cast<const float4*>(x + ((size_t)n * CD + cbase) * HWD);

    float4 acc0 = {0.f,0.f,0.f,0.f}, acc1 = {0.f,0.f,0.f,0.f};
    float4 acc2 = {0.f,0.f,0.f,0.f}, acc3 = {0.f,0.f,0.f,0.f};

    #pragma unroll
    for (int ph = 0; ph < 2; ++ph) {
        const float4* r0 = rows + (ph * 4) * Q4;
        const float4* r1 = r0 + Q4;
        const float4* r2 = r1 + Q4;
        const float4* r3 = r2 + Q4;
        float4 a0 = r0[lane], a1 = r0[lane + 64], a2 = r0[lane + 128];
        float4 b0 = r1[lane], b1 = r1[lane + 64], b2 = r1[lane + 128];
        float4 c0 = r2[lane], c1 = r2[lane + 64], c2 = r2[lane + 128];
        float4 d0 = r3[lane], d1 = r3[lane + 64], d2 = r3[lane + 128];
        float4 a3 = {0.f,0.f,0.f,0.f}, b3 = {0.f,0.f,0.f,0.f};
        float4 c3 = {0.f,0.f,0.f,0.f}, d3 = {0.f,0.f,0.f,0.f};
        if (lane < 4) {
            a3 = r0[192 + lane]; b3 = r1[192 + lane];
            c3 = r2[192 + lane]; d3 = r3[192 + lane];
        }

        const float w0 = w[cbase + ph * 4 + 0];
        const float w1 = w[cbase + ph * 4 + 1];
        const float w2 = w[cbase + ph * 4 + 2];
        const float w3 = w[cbase + ph * 4 + 3];

        a0 = cam4(a0, w0); a1 = cam4(a1, w0); a2 = cam4(a2, w0); a3 = cam4(a3, w0);
        b0 = cam4(b0, w1); b1 = cam4(b1, w1); b2 = cam4(b2, w1); b3 = cam4(b3, w1);
        c0 = cam4(c0, w2); c1 = cam4(c1, w2); c2 = cam4(c2, w2); c3 = cam4(c3, w2);
        d0 = cam4(d0, w3); d1 = cam4(d1, w3); d2 = cam4(d2, w3); d3 = cam4(d3, w3);

        float m0 = fmaxf(fmaxf(max4(a0), max4(a1)), fmaxf(max4(a2), max4(a3)));
        float m1 = fmaxf(fmaxf(max4(b0), max4(b1)), fmaxf(max4(b2), max4(b3)));
        float m2 = fmaxf(fmaxf(max4(c0), max4(c1)), fmaxf(max4(c2), max4(c3)));
        float m3 = fmaxf(fmaxf(max4(d0), max4(d1)), fmaxf(max4(d2), max4(d3)));

        #pragma unroll
        for (int off = 32; off > 0; off >>= 1) {
            m0 = fmaxf(m0, __shfl_xor(m0, off, 64));
            m1 = fmaxf(m1, __shfl_xor(m1, off, 64));
            m2 = fmaxf(m2, __shfl_xor(m2, off, 64));
            m3 = fmaxf(m3, __shfl_xor(m3, off, 64));
        }
        const float t0 = m0 * mu, t1 = m1 * mu, t2 = m2 * mu, t3 = m3 * mu;

        accdrop(acc0, a0, t0); accdrop(acc1, a1, t0); accdrop(acc2, a2, t0); accdrop(acc3, a3, t0);
        accdrop(acc0, b0, t1); accdrop(acc1, b1, t1); accdrop(acc2, b2, t1); accdrop(acc3, b3, t1);
        accdrop(acc0, c0, t2); accdrop(acc1, c1, t2); accdrop(acc2, c2, t2); accdrop(acc3, c3, t2);
        accdrop(acc0, d0, t3); accdrop(acc1, d1, t3); accdrop(acc2, d2, t3); accdrop(acc3, d3, t3);
    }

    drp[wave][lane]       = acc0;
    drp[wave][64 + lane]  = acc1;
    drp[wave][128 + lane] = acc2;
    if (lane < 4) drp[wave][192 + lane] = acc3;
    __syncthreads();

    const float* f = reinterpret_cast<const float*>(&drp[0][0]);
    float* sp = Spart + ((size_t)blockIdx.x * ND + n) * HWD;
    for (int p = t; p < HWD; p += 256)
        sp[p] = f[p] + f[788 + p] + f[2 * 788 + p] + f[3 * 788 + p];
}

// ---------------------------------------------------------------------------
// Reduce (round-8): S[n,p] = sum over 32 chunks of Spart[chunk][n][p].
// ---------------------------------------------------------------------------
__global__ void __launch_bounds__(256) reduce_kernel(const float* __restrict__ Spart,
                                                     float* __restrict__ S) {
    const int j = blockIdx.x * 256 + threadIdx.x;   // 0 .. 50175
    float s = 0.f;
    #pragma unroll
    for (int ch = 0; ch < NCHUNK; ++ch)
        s += Spart[(size_t)ch * ND * HWD + j];
    S[j] = s;
}

// ---------------------------------------------------------------------------
// Mult: thread -> (n, c0, p4); iterates channels c0+64k, k=0..15, keeping
// (n, p4) FIXED so its S float4 is loaded once and reused 16x. Lanes cover
// consecutive p4 -> 1KB/wave linear segments (same coalescing as the known-
// good linear mult); per-thread VMEM requests 48 -> 33. NT stores keep the
// out stream from evicting x (L3-hot after pass1).
// ---------------------------------------------------------------------------
__global__ void __launch_bounds__(256) mult_kernel(const float* __restrict__ x,
                                                   const float* __restrict__ S,
                                                   float* __restrict__ out) {
    const float4* x4 = reinterpret_cast<const float4*>(x);
    const float4* S4 = reinterpret_cast<const float4*>(S);

    const int tid = blockIdx.x * 256 + threadIdx.x;   // 0 .. 802815
    const int n   = tid / (64 * Q4);                  // 0..63
    const int rem = tid - n * (64 * Q4);
    const int c0  = rem / Q4;                         // 0..63
    const int p4  = rem - c0 * Q4;                    // 0..195

    const float4 sv = S4[n * Q4 + p4];                // one S load, reused 16x
    size_t i4 = ((size_t)(n * CD + c0)) * Q4 + p4;

    #pragma unroll 4
    for (int k = 0; k < 16; ++k, i4 += (size_t)64 * Q4) {
        float4 xv = x4[i4];
        float4 o;
        o.x = xv.x * sv.x;
        o.y = xv.y * sv.y;
        o.z = xv.z * sv.z;
        o.w = xv.w * sv.w;
        __builtin_nontemporal_store(*reinterpret_cast<const f32x4*>(&o),
                                    reinterpret_cast<f32x4*>(out) + i4);
    }
}

extern "C" void kernel_launch(void* const* d_in, const int* in_sizes, int n_in,
                              void* d_out, int out_size, void* d_ws, size_t ws_size,
                              hipStream_t stream) {
    const float* x  = (const float*)d_in[0];   // [N, C, H, W] f32
    const float* w  = (const float*)d_in[1];   // [C] f32
    const float* mu = (const float*)d_in[2];   // scalar (1-elem array)
    float* out = (float*)d_out;

    float* Spart = (float*)d_ws;                       // 32*64*784*4 = 6.4 MB
    float* S     = Spart + (size_t)NCHUNK * ND * HWD;  // 64*784 = 200 KB

    // Pass 1: 32 chunks x 64 samples, 256 threads (4 waves x 8 channels)
    dim3 g1(NCHUNK, ND);
    pass1_kernel<<<g1, 256, 0, stream>>>(x, w, mu, Spart);

    // Reduce: 50176 outputs
    reduce_kernel<<<ND * HWD / 256, 256, 0, stream>>>(Spart, S);

    // Mult: 3136 blocks x 256 threads, fixed (n,p4) per thread
    mult_kernel<<<3136, 256, 0, stream>>>(x, S, out);
}

// Round 12
// 98.890 us; speedup vs baseline: 1.2993x; 1.0111x over previous
//
#include <hip/hip_runtime.h>

// Problem shape (fixed by reference): N=64, C=1024, H=W=28 -> HW=784
#define HWD 784
#define Q4  196            // HWD/4 float4 slots per channel row
#define CD  1024
#define ND  64

#define CHPB 32            // channels per pass1 block (4 waves x 8)
#define NCHUNK (CD / CHPB) // 32 partial chunks

typedef float f32x4 __attribute__((ext_vector_type(4)));

__device__ __forceinline__ float4 cam4(float4 v, float wc) {
    float4 r;
    r.x = fmaxf(v.x * wc, 0.f);
    r.y = fmaxf(v.y * wc, 0.f);
    r.z = fmaxf(v.z * wc, 0.f);
    r.w = fmaxf(v.w * wc, 0.f);
    return r;
}
__device__ __forceinline__ float max4(float4 v) {
    return fmaxf(fmaxf(v.x, v.y), fmaxf(v.z, v.w));
}
__device__ __forceinline__ void accdrop(float4& a, float4 c, float thr) {
    a.x += (c.x > thr) ? 0.f : c.x;
    a.y += (c.y > thr) ? 0.f : c.y;
    a.z += (c.z > thr) ? 0.f : c.z;
    a.w += (c.w > thr) ? 0.f : c.w;
}

// ---------------------------------------------------------------------------
// Pass 1 v4: thr_kernel's proven streaming shape (4 float4 loads live,
// one channel per iteration, ~<=64 VGPR -> 8 waves/SIMD) + register
// accumulation of the dropped-sum across the wave's 8 sequential channels.
// Block = (chunk of 32 channels, n), 256 threads = 4 waves.
// #pragma unroll 1 keeps the loop body small so the compiler can't hoist
// all 8 iterations' loads into registers (which would halve occupancy).
// ---------------------------------------------------------------------------
__global__ void __launch_bounds__(256) pass1_kernel(const float* __restrict__ x,
                                                    const float* __restrict__ w,
                                                    const float* __restrict__ mu_p,
                                                    float* __restrict__ Spart) {
    __shared__ float4 drp[4][197];   // wave stride 197*4 = 788 floats

    const int t = threadIdx.x;
    const int wave = t >> 6;
    const int lane = t & 63;
    const int n = blockIdx.y;
    const int cbase = blockIdx.x * CHPB + wave * 8;
    const float mu = mu_p[0];

    const float4* rows = reinterpret_cast<const float4*>(x + ((size_t)n * CD + cbase) * HWD);

    float4 acc0 = {0.f,0.f,0.f,0.f}, acc1 = {0.f,0.f,0.f,0.f};
    float4 acc2 = {0.f,0.f,0.f,0.f}, acc3 = {0.f,0.f,0.f,0.f};

    #pragma unroll 1
    for (int j = 0; j < 8; ++j) {
        const float4* r = rows + j * Q4;
        float4 v0 = r[lane];
        float4 v1 = r[lane + 64];
        float4 v2 = r[lane + 128];
        float4 v3 = (lane < 4) ? r[192 + lane] : float4{0.f,0.f,0.f,0.f};
        const float wc = w[cbase + j];

        v0 = cam4(v0, wc); v1 = cam4(v1, wc); v2 = cam4(v2, wc); v3 = cam4(v3, wc);

        float m = fmaxf(fmaxf(max4(v0), max4(v1)), fmaxf(max4(v2), max4(v3)));
        #pragma unroll
        for (int off = 32; off > 0; off >>= 1)
            m = fmaxf(m, __shfl_xor(m, off, 64));
        const float thr = m * mu;

        accdrop(acc0, v0, thr);
        accdrop(acc1, v1, thr);
        accdrop(acc2, v2, thr);
        accdrop(acc3, v3, thr);      // zeros for lane >= 4: harmless
    }

    drp[wave][lane]       = acc0;
    drp[wave][64 + lane]  = acc1;
    drp[wave][128 + lane] = acc2;
    if (lane < 4) drp[wave][192 + lane] = acc3;
    __syncthreads();

    const float* f = reinterpret_cast<const float*>(&drp[0][0]);
    float* sp = Spart + ((size_t)blockIdx.x * ND + n) * HWD;
    for (int p = t; p < HWD; p += 256)
        sp[p] = f[p] + f[788 + p] + f[2 * 788 + p] + f[3 * 788 + p];
}

// ---------------------------------------------------------------------------
// Reduce: S[n,p] = sum over 32 chunks of Spart[chunk][n][p]. Coalesced.
// ---------------------------------------------------------------------------
__global__ void __launch_bounds__(256) reduce_kernel(const float* __restrict__ Spart,
                                                     float* __restrict__ S) {
    const int j = blockIdx.x * 256 + threadIdx.x;   // 0 .. 50175
    float s = 0.f;
    #pragma unroll
    for (int ch = 0; ch < NCHUNK; ++ch)
        s += Spart[(size_t)ch * ND * HWD + j];
    S[j] = s;
}

// ---------------------------------------------------------------------------
// Mult (round-11, measured ~45us): thread -> (n, c0, p4); iterates channels
// c0+64k keeping (n,p4) fixed so its S float4 loads once, reused 16x. Lanes
// cover consecutive p4 -> 1KB/wave linear segments. NT stores keep the out
// stream from evicting x (L3-hot after pass1).
// ---------------------------------------------------------------------------
__global__ void __launch_bounds__(256) mult_kernel(const float* __restrict__ x,
                                                   const float* __restrict__ S,
                                                   float* __restrict__ out) {
    const float4* x4 = reinterpret_cast<const float4*>(x);
    const float4* S4 = reinterpret_cast<const float4*>(S);

    const int tid = blockIdx.x * 256 + threadIdx.x;   // 0 .. 802815
    const int n   = tid / (64 * Q4);                  // 0..63
    const int rem = tid - n * (64 * Q4);
    const int c0  = rem / Q4;                         // 0..63
    const int p4  = rem - c0 * Q4;                    // 0..195

    const float4 sv = S4[n * Q4 + p4];                // one S load, reused 16x
    size_t i4 = ((size_t)(n * CD + c0)) * Q4 + p4;

    #pragma unroll 4
    for (int k = 0; k < 16; ++k, i4 += (size_t)64 * Q4) {
        float4 xv = x4[i4];
        float4 o;
        o.x = xv.x * sv.x;
        o.y = xv.y * sv.y;
        o.z = xv.z * sv.z;
        o.w = xv.w * sv.w;
        __builtin_nontemporal_store(*reinterpret_cast<const f32x4*>(&o),
                                    reinterpret_cast<f32x4*>(out) + i4);
    }
}

extern "C" void kernel_launch(void* const* d_in, const int* in_sizes, int n_in,
                              void* d_out, int out_size, void* d_ws, size_t ws_size,
                              hipStream_t stream) {
    const float* x  = (const float*)d_in[0];   // [N, C, H, W] f32
    const float* w  = (const float*)d_in[1];   // [C] f32
    const float* mu = (const float*)d_in[2];   // scalar (1-elem array)
    float* out = (float*)d_out;

    float* Spart = (float*)d_ws;                       // 32*64*784*4 = 6.4 MB
    float* S     = Spart + (size_t)NCHUNK * ND * HWD;  // 64*784 = 200 KB

    // Pass 1: 32 chunks x 64 samples, 256 threads (4 waves x 8 channels)
    dim3 g1(NCHUNK, ND);
    pass1_kernel<<<g1, 256, 0, stream>>>(x, w, mu, Spart);

    // Reduce: 50176 outputs
    reduce_kernel<<<ND * HWD / 256, 256, 0, stream>>>(Spart, S);

    // Mult: 3136 blocks x 256 threads, fixed (n,p4) per thread
    mult_kernel<<<3136, 256, 0, stream>>>(x, S, out);
}